// Round 6
// baseline (62074.084 us; speedup 1.0000x reference)
//
#include <hip/hip_runtime.h>
#include <hip/hip_bf16.h>

#define B_ 256
#define T_ 500
#define I_ 256
#define H_ 512
#define G_ 2048   // 4*H
#define O_ 100

// ---- zero-communication persistent geometry ----
// 16 independent blocks x 512 threads (8 waves). Block owns 16 batch rows and
// ALL 2048 gates -> h feedback is block-internal (LDS double buffer, one
// __syncthreads per step). Blocks never communicate: no atomics, no fences,
// no spin-waits, no cooperative launch -> cannot hang under any scheduling.
// Wave w owns cells [w*64, (w+1)*64) x 4 gate types; weights stream from L2
// (3 MB bf16 fits each XCD's 4 MB L2).

typedef __attribute__((ext_vector_type(8))) short short8;
typedef __attribute__((ext_vector_type(4))) float f32x4;

// ---- workspace layout (bytes) ----
#define WHB_OFF 0u                       // Wh bf16 [2048][512]  2 MB
#define WXB_OFF (G_*H_*2u)               // Wx bf16 [2048][256]  1 MB
#define HT_OFF  (WXB_OFF + G_*I_*2u)     // final h f32 [256][512] 512 KB
// total 3.5 MB

__device__ __forceinline__ float sigm(float v) { return 1.0f / (1.0f + __expf(-v)); }
__device__ __forceinline__ float tanh_fast(float v) { return 2.0f / (1.0f + __expf(-2.0f * v)) - 1.0f; }

__device__ __forceinline__ short f2bf(float f) {
  union { __hip_bfloat16 h; unsigned short u; } cv;
  cv.h = __float2bfloat16(f);
  return (short)cv.u;
}
__device__ __forceinline__ short8 cvt8(float4 a, float4 b) {
  short8 s;
  s[0]=f2bf(a.x); s[1]=f2bf(a.y); s[2]=f2bf(a.z); s[3]=f2bf(a.w);
  s[4]=f2bf(b.x); s[5]=f2bf(b.y); s[6]=f2bf(b.z); s[7]=f2bf(b.w);
  return s;
}

// Cast weights to bf16 once per call.
__global__ void cast_kernel(const float* __restrict__ Wh, const float* __restrict__ Wx,
                            short* __restrict__ Whb, short* __restrict__ Wxb) {
  int idx = blockIdx.x * 256 + threadIdx.x;
  if (idx < G_ * H_) Whb[idx] = f2bf(Wh[idx]);
  if (idx < G_ * I_) Wxb[idx] = f2bf(Wx[idx]);
}

// ================= zero-communication persistent kernel =================
// Per step, per wave: 4 cell-chunks m (16 cells each). For each m: 4 gate-type
// accumulators (q = i,f,g,o), K-loop over 768 (512 h from LDS + 256 x from
// regs), then the cell update for chunk m -- whose sigmoid/tanh VALU work
// overlaps chunk m+1's MFMAs.
__global__ __launch_bounds__(512)
void lstm_nocomm(const float* __restrict__ x,
                 const short* __restrict__ Whb, const short* __restrict__ Wxb,
                 const float* __restrict__ bx, const float* __restrict__ bh,
                 float* __restrict__ hT)
{
  // h double buffer: [2][16 rows][512 cols] bf16, XOR-swizzled (byte ^= (row&7)<<4)
  __shared__ __align__(16) char hlds[32768];

  const int tid = threadIdx.x;
  const int w = tid >> 6;            // wave 0..7 -> cells [w*64, w*64+64)
  const int l = tid & 63;
  const int r = l & 15;              // MFMA row/col selector
  const int u = l >> 4;              // 0..3 -> k-subchunk / output row group
  const int rbase = blockIdx.x * 16; // 16 batch rows per block

  // zero h buffer 0 (t=0 state); 512 threads x 32 B = 16 KB
  {
    float4 z = (float4){0.f, 0.f, 0.f, 0.f};
    *(float4*)(hlds + tid * 32)      = z;
    *(float4*)(hlds + tid * 32 + 16) = z;
  }

  // per-lane biases for the 16 (m,q) gate columns this lane owns
  float bs[4][4];   // [m][q]
  #pragma unroll
  for (int m = 0; m < 4; ++m)
    #pragma unroll
    for (int q = 0; q < 4; ++q) {
      int g = q * H_ + w * 64 + m * 16 + r;
      bs[m][q] = bx[g] + bh[g];
    }

  float c[4][4];    // cell state [m][j], register-resident for all 500 steps
  #pragma unroll
  for (int m = 0; m < 4; ++m)
    #pragma unroll
    for (int j = 0; j < 4; ++j) c[m][j] = 0.f;

  __syncthreads();

  const float* xrow = x + (size_t)(rbase + r) * T_ * I_;

  for (int t = 0; t < T_; ++t) {
    const int cur = t & 1, nxt = cur ^ 1;

    // ---- A-fragments for this step ----
    // h-part: 16 k-steps from LDS (swizzled), shared across all m,q
    short8 ah[16];
    #pragma unroll
    for (int ks = 0; ks < 16; ++ks) {
      int byte = cur * 16384 + r * 1024 + ks * 64 + u * 16;
      byte ^= (r & 7) << 4;
      ah[ks] = *(const short8*)(hlds + byte);
    }
    // x-part: 8 k-steps, f32 -> bf16 in-register (x is IC-resident after warmup)
    short8 ax[8];
    {
      const float* xp = xrow + (size_t)t * I_ + u * 8;
      #pragma unroll
      for (int kx = 0; kx < 8; ++kx) {
        float4 f0 = *(const float4*)(xp + kx * 32);
        float4 f1 = *(const float4*)(xp + kx * 32 + 4);
        ax[kx] = cvt8(f0, f1);
      }
    }

    // ---- 4 cell-chunks; chunk m's nonlinearities overlap chunk m+1's MFMAs ----
    #pragma unroll
    for (int m = 0; m < 4; ++m) {
      const int col = w * 64 + m * 16 + r;     // this lane's cell column
      f32x4 acc[4];
      #pragma unroll
      for (int q = 0; q < 4; ++q)
        acc[q] = (f32x4){bs[m][q], bs[m][q], bs[m][q], bs[m][q]};

      // h-part: K = 0..511, B streamed from L2 (Whb row-major [2048][512])
      #pragma unroll
      for (int ks = 0; ks < 16; ++ks) {
        #pragma unroll
        for (int q = 0; q < 4; ++q) {
          const short* bp = Whb + (size_t)(q * H_ + col) * H_ + ks * 32 + u * 8;
          acc[q] = __builtin_amdgcn_mfma_f32_16x16x32_bf16(ah[ks], *(const short8*)bp, acc[q], 0, 0, 0);
        }
      }
      // x-part: K = 512..767 (Wxb row-major [2048][256])
      #pragma unroll
      for (int kx = 0; kx < 8; ++kx) {
        #pragma unroll
        for (int q = 0; q < 4; ++q) {
          const short* bp = Wxb + (size_t)(q * H_ + col) * I_ + kx * 32 + u * 8;
          acc[q] = __builtin_amdgcn_mfma_f32_16x16x32_bf16(ax[kx], *(const short8*)bp, acc[q], 0, 0, 0);
        }
      }

      // cell update: lane holds i,f,g,o for rows rbase + u*4 + j, cell `col`
      #pragma unroll
      for (int j = 0; j < 4; ++j) {
        float ig = sigm(acc[0][j]);
        float fg = sigm(acc[1][j]);
        float gg = tanh_fast(acc[2][j]);
        float og = sigm(acc[3][j]);
        float cn = c[m][j] * fg + ig * gg;
        c[m][j] = cn;
        float hn = og * tanh_fast(cn);
        const int row = u * 4 + j;
        int byte = nxt * 16384 + row * 1024 + col * 2;
        byte ^= (row & 7) << 4;
        *(short*)(hlds + byte) = f2bf(hn);
        if (t == T_ - 1)
          hT[(size_t)(rbase + row) * H_ + col] = hn;   // f32 final h for FC
      }
    }

    __syncthreads();   // h_{t+1} writes visible to all waves of this block
  }
}

// out[b][o] = hT[b,:] . Wfc[o,:] + bfc[o]
__global__ __launch_bounds__(128)
void fc_f32(const float* __restrict__ hT, const float* __restrict__ Wfc,
            const float* __restrict__ bfc, float* __restrict__ out) {
  int b = blockIdx.x;
  int o = threadIdx.x;
  if (o >= O_) return;
  const float* hr = hT + (size_t)b * H_;
  const float* wr = Wfc + (size_t)o * H_;
  float s = 0.f;
  #pragma unroll 4
  for (int k = 0; k < H_; k += 4) {
    float4 hv = *reinterpret_cast<const float4*>(hr + k);
    float4 wv = *reinterpret_cast<const float4*>(wr + k);
    s += hv.x * wv.x + hv.y * wv.y + hv.z * wv.z + hv.w * wv.w;
  }
  out[b * O_ + o] = s + bfc[o];
}

extern "C" void kernel_launch(void* const* d_in, const int* in_sizes, int n_in,
                              void* d_out, int out_size, void* d_ws, size_t ws_size,
                              hipStream_t stream) {
  const float* x   = (const float*)d_in[0];
  const float* Wx  = (const float*)d_in[1];
  const float* bx  = (const float*)d_in[2];
  const float* Wh  = (const float*)d_in[3];
  const float* bh  = (const float*)d_in[4];
  const float* Wfc = (const float*)d_in[5];
  const float* bfc = (const float*)d_in[6];
  float* out = (float*)d_out;
  char* ws = (char*)d_ws;

  short* Whb = (short*)(ws + WHB_OFF);
  short* Wxb = (short*)(ws + WXB_OFF);
  float* hT  = (float*)(ws + HT_OFF);

  cast_kernel<<<(G_ * H_ + 255) / 256, 256, 0, stream>>>(Wh, Wx, Whb, Wxb);
  lstm_nocomm<<<dim3(B_ / 16), dim3(512), 0, stream>>>(x, Whb, Wxb, bx, bh, hT);
  fc_f32<<<dim3(B_), dim3(128), 0, stream>>>(hT, Wfc, bfc, out);
}

// Round 7
// 8858.456 us; speedup vs baseline: 7.0073x; 7.0073x over previous
//
#include <hip/hip_runtime.h>
#include <hip/hip_bf16.h>

#define B_ 256
#define T_ 500
#define I_ 256
#define H_ 512
#define G_ 2048   // 4*H
#define O_ 100

// Multi-launch design (graph-replayed): 500 step kernels, each a global
// barrier. No inter-block communication anywhere -> structurally hang-free.
//
// Step-kernel geometry: 1-D grid of 128 blocks x 256 threads (4 waves).
// Decoded as (rg, cc): rg = 4 row-groups x 64 rows, cc = 32 cell-chunks x 16
// cells. Swizzle puts all 4 rg-blocks of a cell-chunk on the SAME XCD
// (bid%8 == cc%8 under round-robin dispatch) so each 96 KB weight slice is
// fetched into exactly one XCD's L2 per step instead of up to 8.

typedef __attribute__((ext_vector_type(8))) short short8;
typedef __attribute__((ext_vector_type(4))) float f32x4;

// ---- workspace layout (bytes) ----
#define WHB_OFF  0u                              // Wh bf16 [2048][512]    2 MB
#define WXB_OFF  (G_*H_*2u)                      // Wx bf16 [2048][256]    1 MB
#define BSUM_OFF (WXB_OFF + G_*I_*2u)            // bx+bh f32 [2048]       8 KB
#define H0_OFF   (BSUM_OFF + G_*4u)              // h buf0 bf16 [256][512] 256 KB
#define H1_OFF   (H0_OFF + B_*H_*2u)             // h buf1 bf16            256 KB
#define C_OFF    (H1_OFF + B_*H_*2u)             // c f32 [256][512]       512 KB
// total ~4.0 MB

__device__ __forceinline__ float sigm(float v) { return 1.0f / (1.0f + __expf(-v)); }
__device__ __forceinline__ float tanh_fast(float v) { return 2.0f / (1.0f + __expf(-2.0f * v)) - 1.0f; }

__device__ __forceinline__ short f2bf(float f) {
  union { __hip_bfloat16 h; unsigned short u; } cv;
  cv.h = __float2bfloat16(f);
  return (short)cv.u;
}
__device__ __forceinline__ short8 cvt8(float4 a, float4 b) {
  short8 s;
  s[0]=f2bf(a.x); s[1]=f2bf(a.y); s[2]=f2bf(a.z); s[3]=f2bf(a.w);
  s[4]=f2bf(b.x); s[5]=f2bf(b.y); s[6]=f2bf(b.z); s[7]=f2bf(b.w);
  return s;
}

// Cast weights to bf16 once per call; precompute bias sum.
__global__ void cast_kernel(const float* __restrict__ Wh, const float* __restrict__ Wx,
                            const float* __restrict__ bx, const float* __restrict__ bh,
                            short* __restrict__ Whb, short* __restrict__ Wxb,
                            float* __restrict__ bsum) {
  int idx = blockIdx.x * 256 + threadIdx.x;
  if (idx < G_ * H_) Whb[idx] = f2bf(Wh[idx]);
  if (idx < G_ * I_) Wxb[idx] = f2bf(Wx[idx]);
  if (idx < G_)      bsum[idx] = bx[idx] + bh[idx];
}

// One LSTM timestep. Wave w of block (rg,cc) computes the 16x64 gate tile for
// rows [rg*64 + w*16, +16) x cells [cc*16, +16) x 4 gate types; each lane ends
// holding i,f,g,o for the same (row, cell) -> local cell update, no cross-lane.
__global__ __launch_bounds__(256)
void lstm_step2(const float* __restrict__ x, int t,
                const short* __restrict__ Whb, const short* __restrict__ Wxb,
                const float* __restrict__ bsum,
                const short* __restrict__ h_in,
                unsigned short* __restrict__ h_out,
                float* __restrict__ c) {
  const int tid = threadIdx.x;
  const int w = tid >> 6, l = tid & 63;
  const int r = l & 15;              // A-row / B-col / D-col selector
  const int u = l >> 4;              // k-subchunk (8 elems) / D-row group
  const int bid = blockIdx.x;
  const int x8 = bid & 7;            // XCD slot under round-robin dispatch
  const int kk_ = bid >> 3;
  const int cc = x8 + ((kk_ & 3) << 3);   // cell chunk 0..31 (cc%8 == bid%8)
  const int rg = kk_ >> 2;                // row group 0..3
  const int brow = rg * 64 + w * 16;
  const int cbase = cc * 16;
  const int cell = cbase + r;

  f32x4 acc[4];
  #pragma unroll
  for (int q = 0; q < 4; ++q) {
    float bb = bsum[q * H_ + cell];
    acc[q] = (f32x4){bb, bb, bb, bb};
  }

  // ---- K part 1: previous h (bf16), K = 0..511 ----
  const short* ha = h_in + (size_t)(brow + r) * H_ + u * 8;
  #pragma unroll
  for (int kk = 0; kk < 16; ++kk) {
    short8 a = *(const short8*)(ha + kk * 32);
    #pragma unroll
    for (int q = 0; q < 4; ++q) {
      const short* bp = Whb + (size_t)(q * H_ + cell) * H_ + kk * 32 + u * 8;
      acc[q] = __builtin_amdgcn_mfma_f32_16x16x32_bf16(a, *(const short8*)bp, acc[q], 0, 0, 0);
    }
  }

  // ---- K part 2: x_t (f32 -> bf16 in-register), K = 512..767 ----
  const float* xrow = x + ((size_t)(brow + r) * T_ + t) * I_ + u * 8;
  #pragma unroll
  for (int kx = 0; kx < 8; ++kx) {
    float4 f0 = *(const float4*)(xrow + kx * 32);
    float4 f1 = *(const float4*)(xrow + kx * 32 + 4);
    short8 a = cvt8(f0, f1);
    #pragma unroll
    for (int q = 0; q < 4; ++q) {
      const short* bp = Wxb + (size_t)(q * H_ + cell) * I_ + kx * 32 + u * 8;
      acc[q] = __builtin_amdgcn_mfma_f32_16x16x32_bf16(a, *(const short8*)bp, acc[q], 0, 0, 0);
    }
  }

  // ---- cell update: lane holds i,f,g,o for (row = brow + u*4 + j, cell) ----
  #pragma unroll
  for (int j = 0; j < 4; ++j) {
    const int row = brow + u * 4 + j;
    const size_t ci = (size_t)row * H_ + cell;
    float ig = sigm(acc[0][j]);
    float fg = sigm(acc[1][j]);
    float gg = tanh_fast(acc[2][j]);
    float og = sigm(acc[3][j]);
    float cn = c[ci] * fg + ig * gg;
    c[ci] = cn;
    h_out[ci] = (unsigned short)f2bf(og * tanh_fast(cn));
  }
}

// out[b][o] = h_final[b,:] . Wfc[o,:] + bfc[o]   (h_final is bf16)
__global__ __launch_bounds__(128)
void fc_bf16(const unsigned short* __restrict__ h, const float* __restrict__ Wfc,
             const float* __restrict__ bfc, float* __restrict__ out) {
  int b = blockIdx.x;
  int o = threadIdx.x;
  if (o >= O_) return;
  const unsigned short* hr = h + (size_t)b * H_;
  const float* wr = Wfc + (size_t)o * H_;
  float s = 0.f;
  #pragma unroll 4
  for (int k = 0; k < H_; k += 8) {
    short8 hv = *(const short8*)(hr + k);
    #pragma unroll
    for (int j = 0; j < 8; ++j) {
      union { unsigned int uu; float f; } cv;
      cv.uu = ((unsigned int)(unsigned short)hv[j]) << 16;
      s += cv.f * wr[k + j];
    }
  }
  out[b * O_ + o] = s + bfc[o];
}

extern "C" void kernel_launch(void* const* d_in, const int* in_sizes, int n_in,
                              void* d_out, int out_size, void* d_ws, size_t ws_size,
                              hipStream_t stream) {
  const float* x   = (const float*)d_in[0];
  const float* Wx  = (const float*)d_in[1];
  const float* bx  = (const float*)d_in[2];
  const float* Wh  = (const float*)d_in[3];
  const float* bh  = (const float*)d_in[4];
  const float* Wfc = (const float*)d_in[5];
  const float* bfc = (const float*)d_in[6];
  float* out = (float*)d_out;
  char* ws = (char*)d_ws;

  short* Whb  = (short*)(ws + WHB_OFF);
  short* Wxb  = (short*)(ws + WXB_OFF);
  float* bsum = (float*)(ws + BSUM_OFF);
  unsigned short* h0 = (unsigned short*)(ws + H0_OFF);
  unsigned short* h1 = (unsigned short*)(ws + H1_OFF);
  float* cbuf = (float*)(ws + C_OFF);

  // h0 = 0 (bf16 zero is bit-zero), c = 0
  hipMemsetAsync(ws + H0_OFF, 0, B_ * H_ * 2, stream);
  hipMemsetAsync(ws + C_OFF,  0, B_ * H_ * 4, stream);

  cast_kernel<<<(G_ * H_ + 255) / 256, 256, 0, stream>>>(Wh, Wx, bx, bh, Whb, Wxb, bsum);

  for (int t = 0; t < T_; ++t) {
    const unsigned short* hin = (t & 1) ? h1 : h0;
    unsigned short* hout      = (t & 1) ? h0 : h1;
    lstm_step2<<<dim3(128), dim3(256), 0, stream>>>(x, t, Whb, Wxb, bsum,
                                                    (const short*)hin, hout, cbuf);
  }

  // T even -> final h is in h0
  fc_bf16<<<dim3(B_), dim3(128), 0, stream>>>(h0, Wfc, bfc, out);
}

// Round 9
// 5380.893 us; speedup vs baseline: 11.5360x; 1.6463x over previous
//
#include <hip/hip_runtime.h>
#include <hip/hip_bf16.h>

#define B_ 256
#define T_ 500
#define I_ 256
#define H_ 512
#define G_ 2048   // 4*H
#define O_ 100

// Multi-launch design (graph-replayed): 500 step kernels (each a global
// barrier), zero inter-block communication -> structurally hang-free.
//
// Round-7 lesson: step time ~ bytes-per-CU (L2 invalidated per dispatch; IC
// re-pull is latency-bound). So: 256 blocks x 128 thr (round-1 proven layout,
// 1 block/CU) and cut bytes/CU by precomputing xg = x@Wx^T + bx + bh for all
// timesteps in one big parallel GEMM (removes Wx slice + x f32 stream from
// every step: 160 KB/CU -> 100 KB/CU).

typedef __attribute__((ext_vector_type(8))) short short8;
typedef __attribute__((ext_vector_type(4))) float f32x4;

// ---- workspace layout (bytes) ----
#define WHB_OFF  0ull
#define WXB_OFF  (WHB_OFF + (unsigned long long)G_*H_*2)      // Wh bf16  2 MB
#define BSUM_OFF (WXB_OFF + (unsigned long long)G_*I_*2)      // Wx bf16  1 MB
#define H0_OFF   (BSUM_OFF + (unsigned long long)G_*4)        // bx+bh    8 KB
#define H1_OFF   (H0_OFF + (unsigned long long)B_*H_*2)       // h0 bf16  256 KB
#define C_OFF    (H1_OFF + (unsigned long long)B_*H_*2)       // h1 bf16  256 KB
#define XG_OFF   (C_OFF + (unsigned long long)B_*H_*4)        // c f32    512 KB
#define XG_BYTES ((unsigned long long)T_*B_*G_*2)             // xg bf16  512 MB

__device__ __forceinline__ float sigm(float v) { return 1.0f / (1.0f + __expf(-v)); }
__device__ __forceinline__ float tanh_fast(float v) { return 2.0f / (1.0f + __expf(-2.0f * v)) - 1.0f; }

__device__ __forceinline__ short f2bf(float f) {
  union { __hip_bfloat16 h; unsigned short u; } cv;
  cv.h = __float2bfloat16(f);
  return (short)cv.u;
}
__device__ __forceinline__ float bf2f(unsigned short u) {
  union { unsigned int v; float f; } cv;
  cv.v = ((unsigned int)u) << 16;
  return cv.f;
}
__device__ __forceinline__ short8 cvt8(float4 a, float4 b) {
  short8 s;
  s[0]=f2bf(a.x); s[1]=f2bf(a.y); s[2]=f2bf(a.z); s[3]=f2bf(a.w);
  s[4]=f2bf(b.x); s[5]=f2bf(b.y); s[6]=f2bf(b.z); s[7]=f2bf(b.w);
  return s;
}

// Cast weights to bf16 once per call; precompute bias sum.
__global__ void cast_kernel(const float* __restrict__ Wh, const float* __restrict__ Wx,
                            const float* __restrict__ bx, const float* __restrict__ bh,
                            short* __restrict__ Whb, short* __restrict__ Wxb,
                            float* __restrict__ bsum) {
  int idx = blockIdx.x * 256 + threadIdx.x;
  if (idx < G_ * H_) Whb[idx] = f2bf(Wh[idx]);
  if (idx < G_ * I_) Wxb[idx] = f2bf(Wx[idx]);
  if (idx < G_)      bsum[idx] = bx[idx] + bh[idx];
}

// xg[t][b][g] = sum_i x[b][t][i]*Wx[g][i] + bx[g] + bh[g], stored bf16.
// Grid (T, 8): block owns 256 gates for one t; wave w owns 64 of them, loops
// 16 row-tiles of 16 batch rows. Wx slice (32 KB/wave) lives in 128 VGPRs.
__global__ __launch_bounds__(256, 1)
void xg_gemm(const float* __restrict__ x, const short* __restrict__ Wxb,
             const float* __restrict__ bsum, unsigned short* __restrict__ xg) {
  const int t  = blockIdx.x;
  const int gy = blockIdx.y;
  const int tid = threadIdx.x;
  const int w = tid >> 6, l = tid & 63, r = l & 15, u = l >> 4;
  const int gbase = gy * 256 + w * 64;

  short8 wxr[4][8];
  #pragma unroll
  for (int nq = 0; nq < 4; ++nq)
    #pragma unroll
    for (int kc = 0; kc < 8; ++kc)
      wxr[nq][kc] = *(const short8*)(Wxb + (size_t)(gbase + nq*16 + r) * I_ + kc*32 + u*8);

  float bs[4];
  #pragma unroll
  for (int nq = 0; nq < 4; ++nq) bs[nq] = bsum[gbase + nq*16 + r];

  for (int m = 0; m < 16; ++m) {
    const int brow = m * 16;
    short8 ax[8];
    const float* xp = x + ((size_t)(brow + r) * T_ + t) * I_ + u * 8;
    #pragma unroll
    for (int kc = 0; kc < 8; ++kc) {
      float4 f0 = *(const float4*)(xp + kc*32);
      float4 f1 = *(const float4*)(xp + kc*32 + 4);
      ax[kc] = cvt8(f0, f1);
    }
    f32x4 acc[4];
    #pragma unroll
    for (int nq = 0; nq < 4; ++nq) acc[nq] = (f32x4){bs[nq], bs[nq], bs[nq], bs[nq]};
    #pragma unroll
    for (int kc = 0; kc < 8; ++kc)
      #pragma unroll
      for (int nq = 0; nq < 4; ++nq)
        acc[nq] = __builtin_amdgcn_mfma_f32_16x16x32_bf16(ax[kc], wxr[nq][kc], acc[nq], 0, 0, 0);
    // D: col = gbase+nq*16+r, row = brow + u*4 + j
    #pragma unroll
    for (int nq = 0; nq < 4; ++nq)
      #pragma unroll
      for (int j = 0; j < 4; ++j)
        xg[((size_t)t * B_ + brow + u*4 + j) * G_ + gbase + nq*16 + r] =
            (unsigned short)f2bf(acc[nq][j]);
  }
}

// One LSTM timestep, xg-precomputed variant: gates = xg_t + h@Wh^T.
// Grid (32 cc, 8 rg) x 128 thr (2 waves) -- round-1 proven geometry.
__global__ __launch_bounds__(128)
void lstm_step_xg(const unsigned short* __restrict__ xg, int t,
                  const short* __restrict__ Whb,
                  const unsigned short* __restrict__ h_in,
                  unsigned short* __restrict__ h_out,
                  float* __restrict__ c) {
  const int tid = threadIdx.x;
  const int w = tid >> 6, l = tid & 63, r = l & 15, u = l >> 4;
  const int brow = blockIdx.y * 32 + w * 16;
  const int cell = blockIdx.x * 16 + r;

  // acc init from xg (biases already folded in)
  f32x4 acc[4];
  const unsigned short* xq = xg + ((size_t)t * B_ + brow) * G_;
  #pragma unroll
  for (int q = 0; q < 4; ++q)
    #pragma unroll
    for (int j = 0; j < 4; ++j)
      acc[q][j] = bf2f(xq[(size_t)(u*4 + j) * G_ + q*H_ + cell]);

  // A-frags (h rows) hoisted into regs: 16 x 16B
  const unsigned short* ha = h_in + (size_t)(brow + r) * H_ + u * 8;
  short8 ah[16];
  #pragma unroll
  for (int kk = 0; kk < 16; ++kk) ah[kk] = *(const short8*)(ha + kk * 32);

  // h-part: K = 512, B streamed from L2/IC
  #pragma unroll
  for (int kk = 0; kk < 16; ++kk) {
    #pragma unroll
    for (int q = 0; q < 4; ++q) {
      const short* bp = Whb + (size_t)(q * H_ + cell) * H_ + kk * 32 + u * 8;
      acc[q] = __builtin_amdgcn_mfma_f32_16x16x32_bf16(ah[kk], *(const short8*)bp, acc[q], 0, 0, 0);
    }
  }

  // cell update: lane holds i,f,g,o for (row = brow + u*4 + j, cell)
  #pragma unroll
  for (int j = 0; j < 4; ++j) {
    const size_t ci = (size_t)(brow + u*4 + j) * H_ + cell;
    float ig = sigm(acc[0][j]);
    float fg = sigm(acc[1][j]);
    float gg = tanh_fast(acc[2][j]);
    float og = sigm(acc[3][j]);
    float cn = c[ci] * fg + ig * gg;
    c[ci] = cn;
    h_out[ci] = (unsigned short)f2bf(og * tanh_fast(cn));
  }
}

// Fallback step (round-1 proven): fused x-part, used when ws can't hold xg.
__global__ __launch_bounds__(128)
void lstm_step_fb(const float* __restrict__ x, int t,
                  const short* __restrict__ Whb, const short* __restrict__ Wxb,
                  const float* __restrict__ bsum,
                  const unsigned short* __restrict__ h_in,
                  unsigned short* __restrict__ h_out,
                  float* __restrict__ c) {
  const int tid = threadIdx.x;
  const int w = tid >> 6, l = tid & 63, r = l & 15, u = l >> 4;
  const int brow = blockIdx.y * 32 + w * 16;
  const int cell = blockIdx.x * 16 + r;

  f32x4 acc[4];
  #pragma unroll
  for (int q = 0; q < 4; ++q) {
    float bb = bsum[q * H_ + cell];
    acc[q] = (f32x4){bb, bb, bb, bb};
  }

  const unsigned short* ha = h_in + (size_t)(brow + r) * H_ + u * 8;
  #pragma unroll
  for (int kk = 0; kk < 16; ++kk) {
    short8 a = *(const short8*)(ha + kk * 32);
    #pragma unroll
    for (int q = 0; q < 4; ++q) {
      const short* bp = Whb + (size_t)(q * H_ + cell) * H_ + kk * 32 + u * 8;
      acc[q] = __builtin_amdgcn_mfma_f32_16x16x32_bf16(a, *(const short8*)bp, acc[q], 0, 0, 0);
    }
  }

  const float* xrow = x + ((size_t)(brow + r) * T_ + t) * I_ + u * 8;
  #pragma unroll
  for (int kx = 0; kx < 8; ++kx) {
    float4 f0 = *(const float4*)(xrow + kx * 32);
    float4 f1 = *(const float4*)(xrow + kx * 32 + 4);
    short8 a = cvt8(f0, f1);
    #pragma unroll
    for (int q = 0; q < 4; ++q) {
      const short* bp = Wxb + (size_t)(q * H_ + cell) * I_ + kx * 32 + u * 8;
      acc[q] = __builtin_amdgcn_mfma_f32_16x16x32_bf16(a, *(const short8*)bp, acc[q], 0, 0, 0);
    }
  }

  #pragma unroll
  for (int j = 0; j < 4; ++j) {
    const size_t ci = (size_t)(brow + u*4 + j) * H_ + cell;
    float ig = sigm(acc[0][j]);
    float fg = sigm(acc[1][j]);
    float gg = tanh_fast(acc[2][j]);
    float og = sigm(acc[3][j]);
    float cn = c[ci] * fg + ig * gg;
    c[ci] = cn;
    h_out[ci] = (unsigned short)f2bf(og * tanh_fast(cn));
  }
}

// out[b][o] = h_final[b,:] . Wfc[o,:] + bfc[o]   (h_final bf16)
__global__ __launch_bounds__(128)
void fc_bf16(const unsigned short* __restrict__ h, const float* __restrict__ Wfc,
             const float* __restrict__ bfc, float* __restrict__ out) {
  int b = blockIdx.x;
  int o = threadIdx.x;
  if (o >= O_) return;
  const unsigned short* hr = h + (size_t)b * H_;
  const float* wr = Wfc + (size_t)o * H_;
  float s = 0.f;
  #pragma unroll 4
  for (int k = 0; k < H_; k += 8) {
    short8 hv = *(const short8*)(hr + k);
    #pragma unroll
    for (int j = 0; j < 8; ++j) s += bf2f((unsigned short)hv[j]) * wr[k + j];
  }
  out[b * O_ + o] = s + bfc[o];
}

extern "C" void kernel_launch(void* const* d_in, const int* in_sizes, int n_in,
                              void* d_out, int out_size, void* d_ws, size_t ws_size,
                              hipStream_t stream) {
  (void)in_sizes; (void)n_in; (void)out_size;
  const float* x   = (const float*)d_in[0];
  const float* Wx  = (const float*)d_in[1];
  const float* bx  = (const float*)d_in[2];
  const float* Wh  = (const float*)d_in[3];
  const float* bh  = (const float*)d_in[4];
  const float* Wfc = (const float*)d_in[5];
  const float* bfc = (const float*)d_in[6];
  float* out = (float*)d_out;
  char* ws = (char*)d_ws;

  short* Whb  = (short*)(ws + WHB_OFF);
  short* Wxb  = (short*)(ws + WXB_OFF);
  float* bsum = (float*)(ws + BSUM_OFF);
  unsigned short* h0 = (unsigned short*)(ws + H0_OFF);
  unsigned short* h1 = (unsigned short*)(ws + H1_OFF);
  float* cbuf = (float*)(ws + C_OFF);
  unsigned short* xgp = (unsigned short*)(ws + XG_OFF);

  const bool use_xg = (ws_size >= XG_OFF + XG_BYTES);   // deterministic per run

  hipMemsetAsync(ws + H0_OFF, 0, B_ * H_ * 2, stream);  // h0 = 0
  hipMemsetAsync(ws + C_OFF,  0, B_ * H_ * 4, stream);  // c = 0

  cast_kernel<<<(G_ * H_ + 255) / 256, 256, 0, stream>>>(Wh, Wx, bx, bh, Whb, Wxb, bsum);

  if (use_xg) {
    xg_gemm<<<dim3(T_, 8), 256, 0, stream>>>(x, Wxb, bsum, xgp);
    for (int t = 0; t < T_; ++t) {
      const unsigned short* hin = (t & 1) ? h1 : h0;
      unsigned short* hout      = (t & 1) ? h0 : h1;
      lstm_step_xg<<<dim3(32, 8), 128, 0, stream>>>(xgp, t, Whb, hin, hout, cbuf);
    }
  } else {
    for (int t = 0; t < T_; ++t) {
      const unsigned short* hin = (t & 1) ? h1 : h0;
      unsigned short* hout      = (t & 1) ? h0 : h1;
      lstm_step_fb<<<dim3(32, 8), 128, 0, stream>>>(x, t, Whb, Wxb, bsum, hin, hout, cbuf);
    }
  }

  // T even -> final h in h0
  fc_bf16<<<dim3(B_), dim3(128), 0, stream>>>(h0, Wfc, bfc, out);
}